// Round 1
// baseline (370.200 us; speedup 1.0000x reference)
//
#include <hip/hip_runtime.h>

#define EMBED 512
#define EXPAND 1024
#define PNUM 16
#define NLEN 1024
#define CHW (PNUM * NLEN)  // 16384
#define SLABS 64

typedef unsigned short u16;
typedef unsigned int u32;
typedef __bf16 bf16x8 __attribute__((ext_vector_type(8)));
typedef float f32x4 __attribute__((ext_vector_type(4)));

__device__ __forceinline__ u16 f2bf(float f) {
  u32 u = __builtin_bit_cast(u32, f);
  return (u16)((u + 0x7FFFu + ((u >> 16) & 1u)) >> 16);
}
__device__ __forceinline__ float bf2f(u16 h) {
  return __builtin_bit_cast(float, (u32)h << 16);
}
__device__ __forceinline__ void gld16(const u16* g, u16* l) {
  __builtin_amdgcn_global_load_lds((__attribute__((address_space(1))) void*)g,
                                   (__attribute__((address_space(3))) void*)l,
                                   16, 0, 0);
}

// ---------------- Kernel W: weights fp32 -> bf16 ----------------
// WvB[e][c] = Wqkv[1025+e][c] ; WoutB[o][e] = Wout[o][e]
__global__ __launch_bounds__(256) void k_convert_w(
    const float* __restrict__ Wqkv, const float* __restrict__ Wout,
    u16* __restrict__ WvB, u16* __restrict__ WoutB) {
  const int NV = EXPAND * EMBED;  // 524288
  int idx = (blockIdx.x * 256 + threadIdx.x) * 4;
  if (idx < NV) {
    float4 v = *(const float4*)(Wqkv + (size_t)(1 + EXPAND) * EMBED + idx);
    uint2 u = make_uint2((u32)f2bf(v.x) | ((u32)f2bf(v.y) << 16),
                         (u32)f2bf(v.z) | ((u32)f2bf(v.w) << 16));
    *(uint2*)(WvB + idx) = u;
  } else {
    int j = idx - NV;
    float4 v = *(const float4*)(Wout + j);
    uint2 u = make_uint2((u32)f2bf(v.x) | ((u32)f2bf(v.y) << 16),
                         (u32)f2bf(v.z) | ((u32)f2bf(v.w) << 16));
    *(uint2*)(WoutB + j) = u;
  }
}

// ---------------- Kernel A: x -> bf16 transposed + query GEMV ----------------
// xbT[slab][n][c] (c contiguous), q[slab][n] = sum_c Wqkv[0][c]*x[c,n]
__global__ __launch_bounds__(256) void k_convert_x(
    const float* __restrict__ x, const float* __restrict__ Wqkv,
    float* __restrict__ q, u16* __restrict__ xbT) {
  const int slab = blockIdx.x >> 2;
  const int b = slab >> 4, p = slab & 15;
  const int n = ((blockIdx.x & 3) << 8) + threadIdx.x;
  const float* xs = x + (size_t)b * (EMBED * CHW) + (size_t)p * NLEN + n;
  u16* dst = xbT + (size_t)slab * (NLEN * EMBED) + (size_t)n * EMBED;
  float qacc = 0.f;
  for (int c0 = 0; c0 < EMBED; c0 += 16) {
    u32 pk[8];
#pragma unroll
    for (int j = 0; j < 16; ++j) {
      float v = xs[(size_t)(c0 + j) * CHW];
      qacc += Wqkv[c0 + j] * v;
      u16 h = f2bf(v);
      pk[j >> 1] = (j & 1) ? (pk[j >> 1] | ((u32)h << 16)) : (u32)h;
    }
    uint4* d4 = (uint4*)(dst + c0);
    d4[0] = make_uint4(pk[0], pk[1], pk[2], pk[3]);
    d4[1] = make_uint4(pk[4], pk[5], pk[6], pk[7]);
  }
  q[slab * NLEN + n] = qacc;
}

// ---------------- Kernel B: per-slab softmax + y + cv ----------------
// scores = softmax(q); y[c] = sum_n xbT[n][c]*scores[n];
// cv[e] = sum_c Wqkv[1+e][c]*y[c] + bqkv[1+e]
__global__ __launch_bounds__(1024) void k_attn(
    const float* __restrict__ q, const u16* __restrict__ xbT,
    const float* __restrict__ Wqkv, const float* __restrict__ bqkv,
    float* __restrict__ cv) {
  __shared__ float sm[NLEN];
  __shared__ float red[16];
  __shared__ float yl[EMBED];
  __shared__ float ypart[16][EMBED];
  const int slab = blockIdx.x;
  const int t = threadIdx.x, w = t >> 6, l = t & 63;

  float qv = q[slab * NLEN + t];
  float m = qv;
#pragma unroll
  for (int sh = 32; sh; sh >>= 1) m = fmaxf(m, __shfl_xor(m, sh, 64));
  if (l == 0) red[w] = m;
  __syncthreads();
  float gm = red[0];
#pragma unroll
  for (int i = 1; i < 16; ++i) gm = fmaxf(gm, red[i]);
  float ev = __expf(qv - gm);
  float sv = ev;
#pragma unroll
  for (int sh = 32; sh; sh >>= 1) sv += __shfl_xor(sv, sh, 64);
  __syncthreads();
  if (l == 0) red[w] = sv;
  __syncthreads();
  float gs = 0.f;
#pragma unroll
  for (int i = 0; i < 16; ++i) gs += red[i];
  sm[t] = ev / gs;
  __syncthreads();

  // y: wave w handles n = ni*16 + w; lane l owns c = {j*64 + l}
  float ya[8] = {0.f, 0.f, 0.f, 0.f, 0.f, 0.f, 0.f, 0.f};
  const u16* xs = xbT + (size_t)slab * (NLEN * EMBED);
  for (int ni = 0; ni < 64; ++ni) {
    const int n = ni * 16 + w;
    const float sc = sm[n];
    const u16* row = xs + (size_t)n * EMBED + l;
#pragma unroll
    for (int j = 0; j < 8; ++j) ya[j] += sc * bf2f(row[j * 64]);
  }
#pragma unroll
  for (int j = 0; j < 8; ++j) ypart[w][j * 64 + l] = ya[j];
  __syncthreads();
  if (t < EMBED) {
    float a = 0.f;
#pragma unroll
    for (int ww = 0; ww < 16; ++ww) a += ypart[ww][t];
    yl[t] = a;
  }
  __syncthreads();

  // cv: wave w handles e = w*64 .. w*64+63
  for (int ei = 0; ei < 64; ++ei) {
    const int e = w * 64 + ei;
    const float* wk = Wqkv + (size_t)(1 + e) * EMBED;
    float a = 0.f;
#pragma unroll
    for (int cc = 0; cc < 8; ++cc) a += wk[cc * 64 + l] * yl[cc * 64 + l];
#pragma unroll
    for (int sh = 32; sh; sh >>= 1) a += __shfl_xor(a, sh, 64);
    if (l == 0) cv[slab * EXPAND + e] = a + bqkv[1 + e];
  }
}

// ---------------- GEMM core: 128x128 tile, BK=64, 4 waves ----------------
// Computes D[128(m),128(n)] = A_tile(128 rows, K) * B_tile(128 rows, K)^T
// Both operands row-major with k contiguous, row stride K.
template <int K>
__device__ __forceinline__ void gemm_tile(const u16* __restrict__ Abase,
                                          const u16* __restrict__ Bbase,
                                          u16* ldsA, u16* ldsB,
                                          f32x4 acc[4][4]) {
  const int t = threadIdx.x;
  const int srow = t >> 3;
  const int scol = (t & 7) << 3;
  const int w = t >> 6, l = t & 63;
  const int wr = (w >> 1) * 64, wc = (w & 1) * 64;
  const int lr = l & 15, lk = (l >> 4) * 8;
  for (int kt = 0; kt < K; kt += 64) {
#pragma unroll
    for (int i = 0; i < 4; ++i) {
      gld16(Abase + (size_t)(srow + 32 * i) * K + kt + scol,
            ldsA + (srow + 32 * i) * 64 + scol);
      gld16(Bbase + (size_t)(srow + 32 * i) * K + kt + scol,
            ldsB + (srow + 32 * i) * 64 + scol);
    }
    __syncthreads();  // drains vmcnt for global_load_lds
#pragma unroll
    for (int kk = 0; kk < 64; kk += 32) {
      bf16x8 af[4], bfr[4];
#pragma unroll
      for (int mi = 0; mi < 4; ++mi)
        af[mi] = *(const bf16x8*)(ldsA + (wr + mi * 16 + lr) * 64 + kk + lk);
#pragma unroll
      for (int ni = 0; ni < 4; ++ni)
        bfr[ni] = *(const bf16x8*)(ldsB + (wc + ni * 16 + lr) * 64 + kk + lk);
#pragma unroll
      for (int mi = 0; mi < 4; ++mi) {
#pragma unroll
        for (int ni = 0; ni < 4; ++ni)
          acc[mi][ni] = __builtin_amdgcn_mfma_f32_16x16x32_bf16(
              af[mi], bfr[ni], acc[mi][ni], 0, 0, 0);
      }
    }
    __syncthreads();
  }
}

// ---------------- GEMM1: midT[n][e] = relu(valueT + bv)*cv, bf16 ----------------
// valueT[n][e] = sum_c xbT[n][c] * WvB[e][c]
__global__ __launch_bounds__(256) void k_gemm1(
    const u16* __restrict__ xbT, const u16* __restrict__ WvB,
    const float* __restrict__ bqkv, const float* __restrict__ cv,
    u16* __restrict__ midT) {
  __shared__ __align__(16) u16 ldsA[128 * 64];
  __shared__ __align__(16) u16 ldsB[128 * 64];
  const int wg = blockIdx.x;
  const int slab = wg >> 6, tn = (wg >> 3) & 7, te = wg & 7;
  const u16* A = xbT + (size_t)slab * (NLEN * EMBED) + (size_t)tn * 128 * EMBED;
  const u16* B = WvB + (size_t)te * 128 * EMBED;
  f32x4 acc[4][4];
  const f32x4 z = {0.f, 0.f, 0.f, 0.f};
#pragma unroll
  for (int i = 0; i < 4; ++i)
#pragma unroll
    for (int j = 0; j < 4; ++j) acc[i][j] = z;
  gemm_tile<EMBED>(A, B, ldsA, ldsB, acc);

  const int t = threadIdx.x, w = t >> 6, l = t & 63;
  const int wr = (w >> 1) * 64, wc = (w & 1) * 64;
  const int lr = l & 15, lq4 = (l >> 4) * 4;
  u16* mt = midT + (size_t)slab * (NLEN * EXPAND);
#pragma unroll
  for (int ni = 0; ni < 4; ++ni) {
    const int e = te * 128 + wc + ni * 16 + lr;
    const float bv = bqkv[1 + EXPAND + e];
    const float cve = cv[slab * EXPAND + e];
#pragma unroll
    for (int mi = 0; mi < 4; ++mi) {
      const int nr = tn * 128 + wr + mi * 16 + lq4;
#pragma unroll
      for (int r = 0; r < 4; ++r) {
        float v = acc[mi][ni][r] + bv;
        v = v > 0.f ? v * cve : 0.f;
        mt[(size_t)(nr + r) * EXPAND + e] = f2bf(v);
      }
    }
  }
}

// ---------------- GEMM2: out[b][o][p][n] = sum_e midT[n][e]*WoutB[o][e] + bout[o] ----------------
__global__ __launch_bounds__(256) void k_gemm2(
    const u16* __restrict__ midT, const u16* __restrict__ WoutB,
    const float* __restrict__ bout, float* __restrict__ out) {
  __shared__ __align__(16) u16 ldsA[128 * 64];
  __shared__ __align__(16) u16 ldsB[128 * 64];
  const int wg = blockIdx.x;
  const int slab = wg >> 5, tn = (wg >> 2) & 7, to = wg & 3;
  const int b = slab >> 4, p = slab & 15;
  const u16* A = midT + (size_t)slab * (NLEN * EXPAND) + (size_t)tn * 128 * EXPAND;
  const u16* B = WoutB + (size_t)to * 128 * EXPAND;
  f32x4 acc[4][4];
  const f32x4 z = {0.f, 0.f, 0.f, 0.f};
#pragma unroll
  for (int i = 0; i < 4; ++i)
#pragma unroll
    for (int j = 0; j < 4; ++j) acc[i][j] = z;
  gemm_tile<EXPAND>(A, B, ldsA, ldsB, acc);

  const int t = threadIdx.x, w = t >> 6, l = t & 63;
  const int wr = (w >> 1) * 64, wc = (w & 1) * 64;
  const int lr = l & 15, lq4 = (l >> 4) * 4;
  float* ob = out + (size_t)b * (EMBED * CHW) + (size_t)p * NLEN;
#pragma unroll
  for (int ni = 0; ni < 4; ++ni) {
    const int o = to * 128 + wc + ni * 16 + lr;
    const float bo = bout[o];
#pragma unroll
    for (int mi = 0; mi < 4; ++mi) {
      const int nr = tn * 128 + wr + mi * 16 + lq4;
      float4 v;
      v.x = acc[mi][ni][0] + bo;
      v.y = acc[mi][ni][1] + bo;
      v.z = acc[mi][ni][2] + bo;
      v.w = acc[mi][ni][3] + bo;
      *(float4*)(ob + (size_t)o * CHW + nr) = v;
    }
  }
}

extern "C" void kernel_launch(void* const* d_in, const int* in_sizes, int n_in,
                              void* d_out, int out_size, void* d_ws, size_t ws_size,
                              hipStream_t stream) {
  const float* x = (const float*)d_in[0];
  const float* Wqkv = (const float*)d_in[1];
  const float* bqkv = (const float*)d_in[2];
  const float* Wout = (const float*)d_in[3];
  const float* bout = (const float*)d_in[4];
  float* out = (float*)d_out;

  char* ws = (char*)d_ws;
  // layout (all sizes multiples of 4KB):
  u16* xbT = (u16*)ws;                              // 64*1024*512*2   = 67108864
  u16* WvB = (u16*)(ws + 67108864);                 // 1024*512*2     = 1048576
  u16* WoutB = (u16*)(ws + 68157440);               // 512*1024*2     = 1048576
  float* q = (float*)(ws + 69206016);               // 64*1024*4      = 262144
  float* cv = (float*)(ws + 69468160);              // 64*1024*4      = 262144
  u16* midT = (u16*)(ws + 69730304);                // 64*1024*1024*2 = 134217728
  // total = 203948032 bytes

  k_convert_w<<<1024, 256, 0, stream>>>(Wqkv, Wout, WvB, WoutB);
  k_convert_x<<<256, 256, 0, stream>>>(x, Wqkv, q, xbT);
  k_attn<<<64, 1024, 0, stream>>>(q, xbT, Wqkv, bqkv, cv);
  k_gemm1<<<4096, 256, 0, stream>>>(xbT, WvB, bqkv, cv, midT);
  k_gemm2<<<2048, 256, 0, stream>>>(midT, WoutB, bout, out);
}

// Round 2
// 359.920 us; speedup vs baseline: 1.0286x; 1.0286x over previous
//
#include <hip/hip_runtime.h>

#define EMBED 512
#define EXPAND 1024
#define PNUM 16
#define NLEN 1024
#define CHW (PNUM * NLEN)  // 16384
#define SLABS 64

typedef unsigned short u16;
typedef unsigned int u32;
typedef __bf16 bf16x8 __attribute__((ext_vector_type(8)));
typedef u16 u16x8 __attribute__((ext_vector_type(8)));
typedef float f32x4 __attribute__((ext_vector_type(4)));

__device__ __forceinline__ u16 f2bf(float f) {
  u32 u = __builtin_bit_cast(u32, f);
  return (u16)((u + 0x7FFFu + ((u >> 16) & 1u)) >> 16);
}
__device__ __forceinline__ float bf2f(u16 h) {
  return __builtin_bit_cast(float, (u32)h << 16);
}
__device__ __forceinline__ void gld16(const u16* g, u16* l) {
  __builtin_amdgcn_global_load_lds((__attribute__((address_space(1))) void*)g,
                                   (__attribute__((address_space(3))) void*)l,
                                   16, 0, 0);
}

// ---------------- Kernel W: weights fp32 -> bf16 ----------------
__global__ __launch_bounds__(256) void k_convert_w(
    const float* __restrict__ Wqkv, const float* __restrict__ Wout,
    u16* __restrict__ WvB, u16* __restrict__ WoutB) {
  const int NV = EXPAND * EMBED;  // 524288
  int idx = (blockIdx.x * 256 + threadIdx.x) * 4;
  if (idx < NV) {
    float4 v = *(const float4*)(Wqkv + (size_t)(1 + EXPAND) * EMBED + idx);
    uint2 u = make_uint2((u32)f2bf(v.x) | ((u32)f2bf(v.y) << 16),
                         (u32)f2bf(v.z) | ((u32)f2bf(v.w) << 16));
    *(uint2*)(WvB + idx) = u;
  } else {
    int j = idx - NV;
    float4 v = *(const float4*)(Wout + j);
    uint2 u = make_uint2((u32)f2bf(v.x) | ((u32)f2bf(v.y) << 16),
                         (u32)f2bf(v.z) | ((u32)f2bf(v.w) << 16));
    *(uint2*)(WoutB + j) = u;
  }
}

// ---------------- Kernel A: x -> bf16 transposed + query GEMV ----------------
__global__ __launch_bounds__(256) void k_convert_x(
    const float* __restrict__ x, const float* __restrict__ Wqkv,
    float* __restrict__ q, u16* __restrict__ xbT) {
  const int slab = blockIdx.x >> 2;
  const int b = slab >> 4, p = slab & 15;
  const int n = ((blockIdx.x & 3) << 8) + threadIdx.x;
  const float* xs = x + (size_t)b * (EMBED * CHW) + (size_t)p * NLEN + n;
  u16* dst = xbT + (size_t)slab * (NLEN * EMBED) + (size_t)n * EMBED;
  float qacc = 0.f;
  for (int c0 = 0; c0 < EMBED; c0 += 16) {
    u32 pk[8];
#pragma unroll
    for (int j = 0; j < 16; ++j) {
      float v = xs[(size_t)(c0 + j) * CHW];
      qacc += Wqkv[c0 + j] * v;
      u16 h = f2bf(v);
      pk[j >> 1] = (j & 1) ? (pk[j >> 1] | ((u32)h << 16)) : (u32)h;
    }
    uint4* d4 = (uint4*)(dst + c0);
    d4[0] = make_uint4(pk[0], pk[1], pk[2], pk[3]);
    d4[1] = make_uint4(pk[4], pk[5], pk[6], pk[7]);
  }
  q[slab * NLEN + n] = qacc;
}

// ---------------- Kernel B: per-slab softmax + y + cv ----------------
__global__ __launch_bounds__(1024) void k_attn(
    const float* __restrict__ q, const u16* __restrict__ xbT,
    const float* __restrict__ Wqkv, const float* __restrict__ bqkv,
    float* __restrict__ cv) {
  __shared__ float sm[NLEN];
  __shared__ float red[16];
  __shared__ float yl[EMBED];
  __shared__ float ypart[16][EMBED];
  const int slab = blockIdx.x;
  const int t = threadIdx.x, w = t >> 6, l = t & 63;

  float qv = q[slab * NLEN + t];
  float m = qv;
#pragma unroll
  for (int sh = 32; sh; sh >>= 1) m = fmaxf(m, __shfl_xor(m, sh, 64));
  if (l == 0) red[w] = m;
  __syncthreads();
  float gm = red[0];
#pragma unroll
  for (int i = 1; i < 16; ++i) gm = fmaxf(gm, red[i]);
  float ev = __expf(qv - gm);
  float sv = ev;
#pragma unroll
  for (int sh = 32; sh; sh >>= 1) sv += __shfl_xor(sv, sh, 64);
  __syncthreads();
  if (l == 0) red[w] = sv;
  __syncthreads();
  float gs = 0.f;
#pragma unroll
  for (int i = 0; i < 16; ++i) gs += red[i];
  sm[t] = ev / gs;
  __syncthreads();

  // y-phase: wave w handles n = ni*16 + w; lane l owns c = l*8 .. l*8+7 (vectorized)
  float ya[8] = {0.f, 0.f, 0.f, 0.f, 0.f, 0.f, 0.f, 0.f};
  const u16* xs = xbT + (size_t)slab * (NLEN * EMBED);
  for (int ni = 0; ni < 64; ++ni) {
    const int n = ni * 16 + w;
    const float sc = sm[n];
    u16x8 v = *(const u16x8*)(xs + (size_t)n * EMBED + l * 8);
#pragma unroll
    for (int j = 0; j < 8; ++j) ya[j] += sc * bf2f(v[j]);
  }
#pragma unroll
  for (int j = 0; j < 8; ++j) ypart[w][l * 8 + j] = ya[j];
  __syncthreads();
  if (t < EMBED) {
    float a = 0.f;
#pragma unroll
    for (int ww = 0; ww < 16; ++ww) a += ypart[ww][t];
    yl[t] = a;
  }
  __syncthreads();

  // cv-phase: wave w handles e = w*64 .. w*64+63; lane l owns c = l*8..l*8+7
  float y0[8];
#pragma unroll
  for (int j = 0; j < 8; ++j) y0[j] = yl[l * 8 + j];
  for (int ei = 0; ei < 64; ++ei) {
    const int e = w * 64 + ei;
    const float* wk = Wqkv + (size_t)(1 + e) * EMBED + l * 8;
    float4 w1 = *(const float4*)(wk);
    float4 w2 = *(const float4*)(wk + 4);
    float a = w1.x * y0[0] + w1.y * y0[1] + w1.z * y0[2] + w1.w * y0[3] +
              w2.x * y0[4] + w2.y * y0[5] + w2.z * y0[6] + w2.w * y0[7];
#pragma unroll
    for (int sh = 32; sh; sh >>= 1) a += __shfl_xor(a, sh, 64);
    if (l == 0) cv[slab * EXPAND + e] = a + bqkv[1 + e];
  }
}

// ---------------- GEMM core: 128x128 tile, BK=32, dbuf prefetch, swizzled LDS ----
// D[128(m),128(n)] = A(128 rows, K) * B(128 rows, K)^T, k contiguous, row stride K.
// LDS: 2 buffers x (A 128x32 | B 128x32) u16 = 32KB total.
// Swizzle: 16B chunk j at row r stored at physical chunk j ^ ((r>>1)&3)
// (pre-swizzled global source, linear gld16 dest, swizzled ds_read addr).
template <int K>
__device__ __forceinline__ void gemm_tile(const u16* __restrict__ Abase,
                                          const u16* __restrict__ Bbase,
                                          u16* lds, f32x4 acc[4][4]) {
  const int t = threadIdx.x;
  const int w = t >> 6, l = t & 63;
  const int wr = (w >> 1) * 64, wc = (w & 1) * 64;
  const int lr = l & 15;
  const int lj = l >> 4;  // k-chunk 0..3 (8 u16 = 16B each)
  const int nsteps = K / 32;

  auto stage = [&](int buf, int kt) {
    u16* lb = lds + buf * 8192;
#pragma unroll
    for (int i = 0; i < 2; ++i) {
      const int c = i * 256 + t;
      const int row = c >> 2;
      const int jl = (c & 3) ^ ((row >> 1) & 3);
      gld16(Abase + (size_t)row * K + kt + jl * 8, lb + c * 8);
      gld16(Bbase + (size_t)row * K + kt + jl * 8, lb + 4096 + c * 8);
    }
  };

  stage(0, 0);
  __syncthreads();
  for (int s = 0; s < nsteps; ++s) {
    if (s + 1 < nsteps) stage((s + 1) & 1, (s + 1) * 32);  // prefetch overlaps MFMA
    const u16* la = lds + (s & 1) * 8192;
    const u16* lbm = la + 4096;
    bf16x8 af[4], bfr[4];
#pragma unroll
    for (int mi = 0; mi < 4; ++mi) {
      const int r = wr + mi * 16 + lr;
      af[mi] = *(const bf16x8*)(la + r * 32 + (lj ^ ((r >> 1) & 3)) * 8);
    }
#pragma unroll
    for (int ni = 0; ni < 4; ++ni) {
      const int r = wc + ni * 16 + lr;
      bfr[ni] = *(const bf16x8*)(lbm + r * 32 + (lj ^ ((r >> 1) & 3)) * 8);
    }
#pragma unroll
    for (int mi = 0; mi < 4; ++mi) {
#pragma unroll
      for (int ni = 0; ni < 4; ++ni)
        acc[mi][ni] = __builtin_amdgcn_mfma_f32_16x16x32_bf16(
            af[mi], bfr[ni], acc[mi][ni], 0, 0, 0);
    }
    __syncthreads();  // drains this step's ds_reads + prefetch vmcnt
  }
}

// ---------------- GEMM1: midT[n][e] = relu(valueT + bv)*cv, bf16 ----------------
// XCD-colocated decode: the 8 te-siblings sharing an xbT A-panel sit at
// blockIdx stride 8 -> same XCD, adjacent in its queue -> L2 reuse.
__global__ __launch_bounds__(256) void k_gemm1(
    const u16* __restrict__ xbT, const u16* __restrict__ WvB,
    const float* __restrict__ bqkv, const float* __restrict__ cv,
    u16* __restrict__ midT) {
  __shared__ __align__(16) u16 lds[2 * 8192];
  const int bid = blockIdx.x;
  const int x = bid & 7, k = bid >> 3;
  const int te = k & 7;
  const int gg = ((k >> 3) << 3) | x;  // 0..511
  const int slab = gg >> 3, tn = gg & 7;
  const u16* A = xbT + (size_t)slab * (NLEN * EMBED) + (size_t)tn * 128 * EMBED;
  const u16* B = WvB + (size_t)te * 128 * EMBED;
  f32x4 acc[4][4];
  const f32x4 z = {0.f, 0.f, 0.f, 0.f};
#pragma unroll
  for (int i = 0; i < 4; ++i)
#pragma unroll
    for (int j = 0; j < 4; ++j) acc[i][j] = z;
  gemm_tile<EMBED>(A, B, lds, acc);

  const int t = threadIdx.x, w = t >> 6, l = t & 63;
  const int wr = (w >> 1) * 64, wc = (w & 1) * 64;
  const int lr = l & 15, lq4 = (l >> 4) * 4;
  u16* mt = midT + (size_t)slab * (NLEN * EXPAND);
#pragma unroll
  for (int ni = 0; ni < 4; ++ni) {
    const int e = te * 128 + wc + ni * 16 + lr;
    const float bv = bqkv[1 + EXPAND + e];
    const float cve = cv[slab * EXPAND + e];
#pragma unroll
    for (int mi = 0; mi < 4; ++mi) {
      const int nr = tn * 128 + wr + mi * 16 + lq4;
#pragma unroll
      for (int r = 0; r < 4; ++r) {
        float v = acc[mi][ni][r] + bv;
        v = v > 0.f ? v * cve : 0.f;
        mt[(size_t)(nr + r) * EXPAND + e] = f2bf(v);
      }
    }
  }
}

// ---------------- GEMM2: out = Wout*mid + bout ----------------
// XCD-colocated decode: 4 to-siblings sharing a midT A-panel -> same XCD.
__global__ __launch_bounds__(256) void k_gemm2(
    const u16* __restrict__ midT, const u16* __restrict__ WoutB,
    const float* __restrict__ bout, float* __restrict__ out) {
  __shared__ __align__(16) u16 lds[2 * 8192];
  const int bid = blockIdx.x;
  const int x = bid & 7, k = bid >> 3;
  const int to = k & 3;
  const int gg = ((k >> 2) << 3) | x;  // 0..511
  const int slab = gg >> 3, tn = gg & 7;
  const int b = slab >> 4, p = slab & 15;
  const u16* A = midT + (size_t)slab * (NLEN * EXPAND) + (size_t)tn * 128 * EXPAND;
  const u16* B = WoutB + (size_t)to * 128 * EXPAND;
  f32x4 acc[4][4];
  const f32x4 z = {0.f, 0.f, 0.f, 0.f};
#pragma unroll
  for (int i = 0; i < 4; ++i)
#pragma unroll
    for (int j = 0; j < 4; ++j) acc[i][j] = z;
  gemm_tile<EXPAND>(A, B, lds, acc);

  const int t = threadIdx.x, w = t >> 6, l = t & 63;
  const int wr = (w >> 1) * 64, wc = (w & 1) * 64;
  const int lr = l & 15, lq4 = (l >> 4) * 4;
  float* ob = out + (size_t)b * (EMBED * CHW) + (size_t)p * NLEN;
#pragma unroll
  for (int ni = 0; ni < 4; ++ni) {
    const int o = to * 128 + wc + ni * 16 + lr;
    const float bo = bout[o];
#pragma unroll
    for (int mi = 0; mi < 4; ++mi) {
      const int nr = tn * 128 + wr + mi * 16 + lq4;
      float4 v;
      v.x = acc[mi][ni][0] + bo;
      v.y = acc[mi][ni][1] + bo;
      v.z = acc[mi][ni][2] + bo;
      v.w = acc[mi][ni][3] + bo;
      *(float4*)(ob + (size_t)o * CHW + nr) = v;
    }
  }
}

extern "C" void kernel_launch(void* const* d_in, const int* in_sizes, int n_in,
                              void* d_out, int out_size, void* d_ws, size_t ws_size,
                              hipStream_t stream) {
  const float* x = (const float*)d_in[0];
  const float* Wqkv = (const float*)d_in[1];
  const float* bqkv = (const float*)d_in[2];
  const float* Wout = (const float*)d_in[3];
  const float* bout = (const float*)d_in[4];
  float* out = (float*)d_out;

  char* ws = (char*)d_ws;
  u16* xbT = (u16*)ws;                 // 67108864 B
  u16* WvB = (u16*)(ws + 67108864);    // 1048576 B
  u16* WoutB = (u16*)(ws + 68157440);  // 1048576 B
  float* q = (float*)(ws + 69206016);  // 262144 B
  float* cv = (float*)(ws + 69468160); // 262144 B
  u16* midT = (u16*)(ws + 69730304);   // 134217728 B

  k_convert_w<<<1024, 256, 0, stream>>>(Wqkv, Wout, WvB, WoutB);
  k_convert_x<<<256, 256, 0, stream>>>(x, Wqkv, q, xbT);
  k_attn<<<64, 1024, 0, stream>>>(q, xbT, Wqkv, bqkv, cv);
  k_gemm1<<<4096, 256, 0, stream>>>(xbT, WvB, bqkv, cv, midT);
  k_gemm2<<<2048, 256, 0, stream>>>(midT, WoutB, bout, out);
}

// Round 3
// 316.514 us; speedup vs baseline: 1.1696x; 1.1371x over previous
//
#include <hip/hip_runtime.h>

#define EMBED 512
#define EXPAND 1024
#define PNUM 16
#define NLEN 1024
#define CHW (PNUM * NLEN)  // 16384
#define SLABS 64

typedef unsigned short u16;
typedef unsigned int u32;
typedef __bf16 bf16x8 __attribute__((ext_vector_type(8)));
typedef u16 u16x8 __attribute__((ext_vector_type(8)));
typedef float f32x4 __attribute__((ext_vector_type(4)));

__device__ __forceinline__ u16 f2bf(float f) {
  u32 u = __builtin_bit_cast(u32, f);
  return (u16)((u + 0x7FFFu + ((u >> 16) & 1u)) >> 16);
}
__device__ __forceinline__ float bf2f(u16 h) {
  return __builtin_bit_cast(float, (u32)h << 16);
}
__device__ __forceinline__ void gld16(const u16* g, u16* l) {
  __builtin_amdgcn_global_load_lds((__attribute__((address_space(1))) void*)g,
                                   (__attribute__((address_space(3))) void*)l,
                                   16, 0, 0);
}
__device__ __forceinline__ f32x4 MFMA(bf16x8 a, bf16x8 b, f32x4 c) {
  return __builtin_amdgcn_mfma_f32_16x16x32_bf16(a, b, c, 0, 0, 0);
}

// ---------------- Kernel W: weights fp32 -> bf16 ----------------
__global__ __launch_bounds__(256) void k_convert_w(
    const float* __restrict__ Wqkv, const float* __restrict__ Wout,
    u16* __restrict__ WvB, u16* __restrict__ WoutB) {
  const int NV = EXPAND * EMBED;  // 524288
  int idx = (blockIdx.x * 256 + threadIdx.x) * 4;
  if (idx < NV) {
    float4 v = *(const float4*)(Wqkv + (size_t)(1 + EXPAND) * EMBED + idx);
    uint2 u = make_uint2((u32)f2bf(v.x) | ((u32)f2bf(v.y) << 16),
                         (u32)f2bf(v.z) | ((u32)f2bf(v.w) << 16));
    *(uint2*)(WvB + idx) = u;
  } else {
    int j = idx - NV;
    float4 v = *(const float4*)(Wout + j);
    uint2 u = make_uint2((u32)f2bf(v.x) | ((u32)f2bf(v.y) << 16),
                         (u32)f2bf(v.z) | ((u32)f2bf(v.w) << 16));
    *(uint2*)(WoutB + j) = u;
  }
}

// ---------------- Kernel A: x -> bf16 transposed + query GEMV partials ------
// 1024 blocks (64 slabs x 16 n-groups of 64); 4 waves each own a c-quarter.
__global__ __launch_bounds__(256) void k_convert_x(
    const float* __restrict__ x, const float* __restrict__ Wqkv,
    float* __restrict__ q, u16* __restrict__ xbT) {
  __shared__ float qp[256];
  const int slab = blockIdx.x >> 4, ng = blockIdx.x & 15;
  const int b = slab >> 4, p = slab & 15;
  const int t = threadIdx.x, w = t >> 6, l = t & 63;
  const int n = ng * 64 + l;
  const float* xs = x + (size_t)b * (EMBED * CHW) + (size_t)p * NLEN + n;
  u16* dst = xbT + (size_t)slab * (NLEN * EMBED) + (size_t)n * EMBED;
  float qacc = 0.f;
  for (int c0 = w * 128; c0 < w * 128 + 128; c0 += 16) {
    u32 pk[8];
#pragma unroll
    for (int j = 0; j < 16; ++j) {
      float v = xs[(size_t)(c0 + j) * CHW];
      qacc += Wqkv[c0 + j] * v;
      u16 h = f2bf(v);
      pk[j >> 1] = (j & 1) ? (pk[j >> 1] | ((u32)h << 16)) : (u32)h;
    }
    uint4* d4 = (uint4*)(dst + c0);
    d4[0] = make_uint4(pk[0], pk[1], pk[2], pk[3]);
    d4[1] = make_uint4(pk[4], pk[5], pk[6], pk[7]);
  }
  qp[t] = qacc;
  __syncthreads();
  if (w == 0) q[(size_t)slab * NLEN + n] = qp[l] + qp[64 + l] + qp[128 + l] + qp[192 + l];
}

// ---------------- attn1: softmax + partial y over an n-quarter --------------
// 256 blocks (slab, quarter) x 256 threads. ypart[slab][qr][512] f32.
__global__ __launch_bounds__(256) void k_attn1(
    const float* __restrict__ q, const u16* __restrict__ xbT,
    float* __restrict__ ypart) {
  __shared__ float red[4];
  __shared__ float sm[256];
  __shared__ float yp[4][512];
  const int slab = blockIdx.x >> 2, qr = blockIdx.x & 3;
  const int t = threadIdx.x, w = t >> 6, l = t & 63;
  const float* qrow = q + (size_t)slab * NLEN;

  float4 q4 = ((const float4*)qrow)[t];
  float m = fmaxf(fmaxf(q4.x, q4.y), fmaxf(q4.z, q4.w));
#pragma unroll
  for (int sh = 32; sh; sh >>= 1) m = fmaxf(m, __shfl_xor(m, sh, 64));
  if (l == 0) red[w] = m;
  __syncthreads();
  float gm = fmaxf(fmaxf(red[0], red[1]), fmaxf(red[2], red[3]));
  float s = __expf(q4.x - gm) + __expf(q4.y - gm) + __expf(q4.z - gm) + __expf(q4.w - gm);
#pragma unroll
  for (int sh = 32; sh; sh >>= 1) s += __shfl_xor(s, sh, 64);
  __syncthreads();
  if (l == 0) red[w] = s;
  __syncthreads();
  float gs = red[0] + red[1] + red[2] + red[3];
  sm[t] = __expf(qrow[qr * 256 + t] - gm) / gs;
  __syncthreads();

  float ya[8] = {0.f, 0.f, 0.f, 0.f, 0.f, 0.f, 0.f, 0.f};
  const u16* xs = xbT + (size_t)slab * (NLEN * EMBED) + (size_t)qr * 256 * EMBED;
  for (int ni = 0; ni < 64; ++ni) {
    const int nloc = ni * 4 + w;
    const float sc = sm[nloc];
    u16x8 v = *(const u16x8*)(xs + (size_t)nloc * EMBED + l * 8);
#pragma unroll
    for (int j = 0; j < 8; ++j) ya[j] += sc * bf2f(v[j]);
  }
#pragma unroll
  for (int j = 0; j < 8; ++j) yp[w][l * 8 + j] = ya[j];
  __syncthreads();
  for (int c = t; c < 512; c += 256)
    ypart[((size_t)slab * 4 + qr) * 512 + c] = yp[0][c] + yp[1][c] + yp[2][c] + yp[3][c];
}

// ---------------- attn2: cv[e] = Wk[e]·y + bk[e] ----------------------------
// 256 blocks (slab, e-chunk of 256) x 256 threads.
__global__ __launch_bounds__(256) void k_attn2(
    const float* __restrict__ ypart, const float* __restrict__ Wqkv,
    const float* __restrict__ bqkv, float* __restrict__ cv) {
  __shared__ float yl[512];
  const int slab = blockIdx.x >> 2, ec = blockIdx.x & 3;
  const int t = threadIdx.x;
  const int e = ec * 256 + t;
  const float* yb = ypart + (size_t)slab * 4 * 512;
  for (int c = t; c < 512; c += 256)
    yl[c] = yb[c] + yb[512 + c] + yb[1024 + c] + yb[1536 + c];
  __syncthreads();
  const float* wk = Wqkv + (size_t)(1 + e) * EMBED;
  float a = 0.f;
#pragma unroll 4
  for (int c0 = 0; c0 < EMBED; c0 += 4) {
    float4 wv = *(const float4*)(wk + c0);
    a += wv.x * yl[c0] + wv.y * yl[c0 + 1] + wv.z * yl[c0 + 2] + wv.w * yl[c0 + 3];
  }
  cv[(size_t)slab * EXPAND + e] = a + bqkv[1 + e];
}

// ---------------- 256x256 8-phase GEMM core ---------------------------------
// D[256(m),256(n)] = A(256 rows,K) * B(256 rows,K)^T, k-contiguous, stride K.
// 512 thr = 8 waves (2m x 4n); per wave 128x64 out = acc[8][4].
// LDS 128KB: 2 K-tile buffers x (A 256x64 | B 256x64) bf16.
// Swizzle: 16B chunk c at row r lives at physical chunk c^(r&7) (both sides).
// Group t: consume buf t&1 (K-tile t); restage SAME buf for K-tile t+2:
//   B-region at ph3 (B reads end ph2), A-region at ph4 (A reads end ph3).
// Boundary wait: counted vmcnt(8) (K-tile t+1's 8 loads are 9th-16th newest).
template <int K, int NT>
__device__ __forceinline__ void gemm256(const u16* __restrict__ Abase,
                                        const u16* __restrict__ Bbase,
                                        u16* lds, f32x4 (&acc)[8][4]) {
  const int t = threadIdx.x;
  const int w = t >> 6, l = t & 63;
  const int wr = w >> 2, wc = w & 3;
  const int lr = l & 15, lj = l >> 4;
  const int rowA0 = wr * 128 + lr;
  const int rowB0 = wc * 64 + lr;

  auto stage = [&](u16* dstBase, const u16* gBase, int kt) {
#pragma unroll
    for (int i = 0; i < 4; ++i) {
      const int s = i * 512 + t;
      const int row = s >> 3;
      const int pch = s & 7;
      gld16(gBase + (size_t)row * K + kt + ((pch ^ (row & 7)) << 3),
            dstBase + s * 8);
    }
  };
  auto rdA = [&](const u16* bufA, int mi, int kc) -> bf16x8 {
    const int row = rowA0 + mi * 16;
    const int ch = kc * 4 + lj;
    return *(const bf16x8*)(bufA + row * 64 + ((ch ^ (row & 7)) << 3));
  };
  auto rdB = [&](const u16* bufB, int ni, int kc) -> bf16x8 {
    const int row = rowB0 + ni * 16;
    const int ch = kc * 4 + lj;
    return *(const bf16x8*)(bufB + row * 64 + ((ch ^ (row & 7)) << 3));
  };

  // prologue: K0 -> buf0, K1 -> buf1 (8 loads each)
  stage(lds, Abase, 0);
  stage(lds + 16384, Bbase, 0);
  stage(lds + 32768, Abase, 64);
  stage(lds + 49152, Bbase, 64);
  asm volatile("s_waitcnt vmcnt(8)" ::: "memory");  // K0 landed
  __builtin_amdgcn_s_barrier();
  __builtin_amdgcn_sched_barrier(0);

#pragma unroll 1
  for (int kt = 0; kt < NT; ++kt) {
    u16* bufA = lds + (kt & 1) * 32768;
    u16* bufB = bufA + 16384;
    const bool st = (kt + 2) < NT;
    const int kt2 = (kt + 2) * 64;
    bf16x8 a0[4][2], a1[4][2], b0[2][2], b1[2][2];

    // ---- phase 1: ds A[M0]+B[N0]; mfma M0N0
#pragma unroll
    for (int mi = 0; mi < 4; ++mi)
#pragma unroll
      for (int kc = 0; kc < 2; ++kc) a0[mi][kc] = rdA(bufA, mi, kc);
#pragma unroll
    for (int ni = 0; ni < 2; ++ni)
#pragma unroll
      for (int kc = 0; kc < 2; ++kc) b0[ni][kc] = rdB(bufB, ni, kc);
    __builtin_amdgcn_s_barrier();
    __builtin_amdgcn_sched_barrier(0);
    __builtin_amdgcn_s_setprio(1);
#pragma unroll
    for (int mi = 0; mi < 4; ++mi)
#pragma unroll
      for (int ni = 0; ni < 2; ++ni)
#pragma unroll
        for (int kc = 0; kc < 2; ++kc)
          acc[mi][ni] = MFMA(a0[mi][kc], b0[ni][kc], acc[mi][ni]);
    __builtin_amdgcn_s_setprio(0);
    __builtin_amdgcn_sched_barrier(0);
    __builtin_amdgcn_s_barrier();
    __builtin_amdgcn_sched_barrier(0);

    // ---- phase 2: ds B[N1]; mfma M0N1
#pragma unroll
    for (int ni = 0; ni < 2; ++ni)
#pragma unroll
      for (int kc = 0; kc < 2; ++kc) b1[ni][kc] = rdB(bufB, ni + 2, kc);
    __builtin_amdgcn_s_barrier();
    __builtin_amdgcn_sched_barrier(0);
    __builtin_amdgcn_s_setprio(1);
#pragma unroll
    for (int mi = 0; mi < 4; ++mi)
#pragma unroll
      for (int ni = 0; ni < 2; ++ni)
#pragma unroll
        for (int kc = 0; kc < 2; ++kc)
          acc[mi][ni + 2] = MFMA(a0[mi][kc], b1[ni][kc], acc[mi][ni + 2]);
    __builtin_amdgcn_s_setprio(0);
    __builtin_amdgcn_sched_barrier(0);
    __builtin_amdgcn_s_barrier();
    __builtin_amdgcn_sched_barrier(0);

    // ---- phase 3: ds A[M1]; stage B(K-tile t+2); mfma M1N1
#pragma unroll
    for (int mi = 0; mi < 4; ++mi)
#pragma unroll
      for (int kc = 0; kc < 2; ++kc) a1[mi][kc] = rdA(bufA, mi + 4, kc);
    if (st) stage(bufB, Bbase, kt2);
    __builtin_amdgcn_s_barrier();
    __builtin_amdgcn_sched_barrier(0);
    __builtin_amdgcn_s_setprio(1);
#pragma unroll
    for (int mi = 0; mi < 4; ++mi)
#pragma unroll
      for (int ni = 0; ni < 2; ++ni)
#pragma unroll
        for (int kc = 0; kc < 2; ++kc)
          acc[mi + 4][ni + 2] = MFMA(a1[mi][kc], b1[ni][kc], acc[mi + 4][ni + 2]);
    __builtin_amdgcn_s_setprio(0);
    __builtin_amdgcn_sched_barrier(0);
    __builtin_amdgcn_s_barrier();
    __builtin_amdgcn_sched_barrier(0);

    // ---- phase 4: stage A(K-tile t+2); mfma M1N0; counted boundary wait
    if (st) stage(bufA, Abase, kt2);
    __builtin_amdgcn_s_barrier();
    __builtin_amdgcn_sched_barrier(0);
    __builtin_amdgcn_s_setprio(1);
#pragma unroll
    for (int mi = 0; mi < 4; ++mi)
#pragma unroll
      for (int ni = 0; ni < 2; ++ni)
#pragma unroll
        for (int kc = 0; kc < 2; ++kc)
          acc[mi + 4][ni] = MFMA(a1[mi][kc], b0[ni][kc], acc[mi + 4][ni]);
    __builtin_amdgcn_s_setprio(0);
    __builtin_amdgcn_sched_barrier(0);
    if (st)
      asm volatile("s_waitcnt vmcnt(8)" ::: "memory");
    else
      asm volatile("s_waitcnt vmcnt(0)" ::: "memory");
    __builtin_amdgcn_s_barrier();
    __builtin_amdgcn_sched_barrier(0);
  }
}

// ---------------- GEMM1: midT[n][e] = relu(valT + bv)*cv, bf16 --------------
// grid 1024 = 64 slabs x 4 tn x 4 te; te-siblings at bid stride 8 (same XCD).
__global__ __launch_bounds__(512, 2) void k_gemm1(
    const u16* __restrict__ xbT, const u16* __restrict__ WvB,
    const float* __restrict__ bqkv, const float* __restrict__ cv,
    u16* __restrict__ midT) {
  __shared__ __align__(16) u16 lds[65536];  // 128 KB
  const int bid = blockIdx.x;
  const int xc = bid & 7, k = bid >> 3;
  const int te = k & 3;
  const int gg = ((k >> 2) << 3) | xc;  // 0..255
  const int slab = gg >> 2, tn = gg & 3;
  const u16* A = xbT + (size_t)slab * (NLEN * EMBED) + (size_t)tn * 256 * EMBED;
  const u16* B = WvB + (size_t)te * 256 * EMBED;
  f32x4 acc[8][4];
  const f32x4 z = {0.f, 0.f, 0.f, 0.f};
#pragma unroll
  for (int i = 0; i < 8; ++i)
#pragma unroll
    for (int j = 0; j < 4; ++j) acc[i][j] = z;
  gemm256<EMBED, 8>(A, B, lds, acc);

  const int t = threadIdx.x, w = t >> 6, l = t & 63;
  const int wr = w >> 2, wc = w & 3;
  const int lr = l & 15, lq4 = (l >> 4) * 4;
  u16* mt = midT + (size_t)slab * (NLEN * EXPAND);
#pragma unroll
  for (int ni = 0; ni < 4; ++ni) {
    const int e = te * 256 + wc * 64 + ni * 16 + lr;
    const float bv = bqkv[1 + EXPAND + e];
    const float cve = cv[(size_t)slab * EXPAND + e];
#pragma unroll
    for (int mi = 0; mi < 8; ++mi) {
      const int nr = tn * 256 + wr * 128 + mi * 16 + lq4;
#pragma unroll
      for (int r = 0; r < 4; ++r) {
        float v = acc[mi][ni][r] + bv;
        v = v > 0.f ? v * cve : 0.f;
        mt[(size_t)(nr + r) * EXPAND + e] = f2bf(v);
      }
    }
  }
}

// ---------------- GEMM2: out = Wout*mid + bout ------------------------------
// grid 512 = 64 slabs x 4 tn x 2 to; to-siblings at bid stride 8 (same XCD).
__global__ __launch_bounds__(512, 2) void k_gemm2(
    const u16* __restrict__ midT, const u16* __restrict__ WoutB,
    const float* __restrict__ bout, float* __restrict__ out) {
  __shared__ __align__(16) u16 lds[65536];  // 128 KB
  const int bid = blockIdx.x;
  const int xc = bid & 7, k = bid >> 3;
  const int to = k & 1;
  const int gg = ((k >> 1) << 3) | xc;  // 0..255
  const int slab = gg >> 2, tn = gg & 3;
  const int b = slab >> 4, p = slab & 15;
  const u16* A = midT + (size_t)slab * (NLEN * EXPAND) + (size_t)tn * 256 * EXPAND;
  const u16* B = WoutB + (size_t)to * 256 * EXPAND;
  f32x4 acc[8][4];
  const f32x4 z = {0.f, 0.f, 0.f, 0.f};
#pragma unroll
  for (int i = 0; i < 8; ++i)
#pragma unroll
    for (int j = 0; j < 4; ++j) acc[i][j] = z;
  gemm256<EXPAND, 16>(A, B, lds, acc);

  const int t = threadIdx.x, w = t >> 6, l = t & 63;
  const int wr = w >> 2, wc = w & 3;
  const int lr = l & 15, lq4 = (l >> 4) * 4;
  float* ob = out + (size_t)b * (EMBED * CHW) + (size_t)p * NLEN;
#pragma unroll
  for (int ni = 0; ni < 4; ++ni) {
    const int o = to * 256 + wc * 64 + ni * 16 + lr;
    const float bo = bout[o];
#pragma unroll
    for (int mi = 0; mi < 8; ++mi) {
      const int nr = tn * 256 + wr * 128 + mi * 16 + lq4;
      float4 v;
      v.x = acc[mi][ni][0] + bo;
      v.y = acc[mi][ni][1] + bo;
      v.z = acc[mi][ni][2] + bo;
      v.w = acc[mi][ni][3] + bo;
      *(float4*)(ob + (size_t)o * CHW + nr) = v;
    }
  }
}

extern "C" void kernel_launch(void* const* d_in, const int* in_sizes, int n_in,
                              void* d_out, int out_size, void* d_ws, size_t ws_size,
                              hipStream_t stream) {
  const float* x = (const float*)d_in[0];
  const float* Wqkv = (const float*)d_in[1];
  const float* bqkv = (const float*)d_in[2];
  const float* Wout = (const float*)d_in[3];
  const float* bout = (const float*)d_in[4];
  float* out = (float*)d_out;

  char* ws = (char*)d_ws;
  u16* xbT = (u16*)ws;                  // 67108864 B
  u16* WvB = (u16*)(ws + 67108864);     // 1048576 B
  u16* WoutB = (u16*)(ws + 68157440);   // 1048576 B
  float* q = (float*)(ws + 69206016);   // 262144 B
  float* cv = (float*)(ws + 69468160);  // 262144 B
  u16* midT = (u16*)(ws + 69730304);    // 134217728 B
  // ypart (512 KB) aliases midT's head: attn2 reads it before gemm1 writes midT
  float* ypart = (float*)(ws + 69730304);

  k_convert_w<<<1024, 256, 0, stream>>>(Wqkv, Wout, WvB, WoutB);
  k_convert_x<<<1024, 256, 0, stream>>>(x, Wqkv, q, xbT);
  k_attn1<<<256, 256, 0, stream>>>(q, xbT, ypart);
  k_attn2<<<256, 256, 0, stream>>>(ypart, Wqkv, bqkv, cv);
  k_gemm1<<<1024, 512, 0, stream>>>(xbT, WvB, bqkv, cv, midT);
  k_gemm2<<<512, 512, 0, stream>>>(midT, WoutB, bout, out);
}

// Round 4
// 300.569 us; speedup vs baseline: 1.2317x; 1.0530x over previous
//
#include <hip/hip_runtime.h>

#define EMBED 512
#define EXPAND 1024
#define PNUM 16
#define NLEN 1024
#define CHW (PNUM * NLEN)  // 16384
#define SLABS 64

typedef unsigned short u16;
typedef unsigned int u32;
typedef __bf16 bf16x8 __attribute__((ext_vector_type(8)));
typedef u16 u16x8 __attribute__((ext_vector_type(8)));
typedef float f32x4 __attribute__((ext_vector_type(4)));

__device__ __forceinline__ u16 f2bf(float f) {
  u32 u = __builtin_bit_cast(u32, f);
  return (u16)((u + 0x7FFFu + ((u >> 16) & 1u)) >> 16);
}
__device__ __forceinline__ float bf2f(u16 h) {
  return __builtin_bit_cast(float, (u32)h << 16);
}
__device__ __forceinline__ void gld16(const u16* g, u16* l) {
  __builtin_amdgcn_global_load_lds((__attribute__((address_space(1))) void*)g,
                                   (__attribute__((address_space(3))) void*)l,
                                   16, 0, 0);
}
__device__ __forceinline__ f32x4 MFMA(bf16x8 a, bf16x8 b, f32x4 c) {
  return __builtin_amdgcn_mfma_f32_16x16x32_bf16(a, b, c, 0, 0, 0);
}

// ---------------- Kernel W: weights fp32 -> bf16 ----------------
__global__ __launch_bounds__(256) void k_convert_w(
    const float* __restrict__ Wqkv, const float* __restrict__ Wout,
    u16* __restrict__ WvB, u16* __restrict__ WoutB) {
  const int NV = EXPAND * EMBED;  // 524288
  int idx = (blockIdx.x * 256 + threadIdx.x) * 4;
  if (idx < NV) {
    float4 v = *(const float4*)(Wqkv + (size_t)(1 + EXPAND) * EMBED + idx);
    uint2 u = make_uint2((u32)f2bf(v.x) | ((u32)f2bf(v.y) << 16),
                         (u32)f2bf(v.z) | ((u32)f2bf(v.w) << 16));
    *(uint2*)(WvB + idx) = u;
  } else {
    int j = idx - NV;
    float4 v = *(const float4*)(Wout + j);
    uint2 u = make_uint2((u32)f2bf(v.x) | ((u32)f2bf(v.y) << 16),
                         (u32)f2bf(v.z) | ((u32)f2bf(v.w) << 16));
    *(uint2*)(WoutB + j) = u;
  }
}

// ---------------- Kernel A: x -> bf16 transposed + query GEMV partials ------
__global__ __launch_bounds__(256) void k_convert_x(
    const float* __restrict__ x, const float* __restrict__ Wqkv,
    float* __restrict__ q, u16* __restrict__ xbT) {
  __shared__ float qp[256];
  const int slab = blockIdx.x >> 4, ng = blockIdx.x & 15;
  const int b = slab >> 4, p = slab & 15;
  const int t = threadIdx.x, w = t >> 6, l = t & 63;
  const int n = ng * 64 + l;
  const float* xs = x + (size_t)b * (EMBED * CHW) + (size_t)p * NLEN + n;
  u16* dst = xbT + (size_t)slab * (NLEN * EMBED) + (size_t)n * EMBED;
  float qacc = 0.f;
  for (int c0 = w * 128; c0 < w * 128 + 128; c0 += 16) {
    u32 pk[8];
#pragma unroll
    for (int j = 0; j < 16; ++j) {
      float v = xs[(size_t)(c0 + j) * CHW];
      qacc += Wqkv[c0 + j] * v;
      u16 h = f2bf(v);
      pk[j >> 1] = (j & 1) ? (pk[j >> 1] | ((u32)h << 16)) : (u32)h;
    }
    uint4* d4 = (uint4*)(dst + c0);
    d4[0] = make_uint4(pk[0], pk[1], pk[2], pk[3]);
    d4[1] = make_uint4(pk[4], pk[5], pk[6], pk[7]);
  }
  qp[t] = qacc;
  __syncthreads();
  if (w == 0) q[(size_t)slab * NLEN + n] = qp[l] + qp[64 + l] + qp[128 + l] + qp[192 + l];
}

// ---------------- attn1: softmax + partial y over an n-quarter --------------
__global__ __launch_bounds__(256) void k_attn1(
    const float* __restrict__ q, const u16* __restrict__ xbT,
    float* __restrict__ ypart) {
  __shared__ float red[4];
  __shared__ float sm[256];
  __shared__ float yp[4][512];
  const int slab = blockIdx.x >> 2, qr = blockIdx.x & 3;
  const int t = threadIdx.x, w = t >> 6, l = t & 63;
  const float* qrow = q + (size_t)slab * NLEN;

  float4 q4 = ((const float4*)qrow)[t];
  float m = fmaxf(fmaxf(q4.x, q4.y), fmaxf(q4.z, q4.w));
#pragma unroll
  for (int sh = 32; sh; sh >>= 1) m = fmaxf(m, __shfl_xor(m, sh, 64));
  if (l == 0) red[w] = m;
  __syncthreads();
  float gm = fmaxf(fmaxf(red[0], red[1]), fmaxf(red[2], red[3]));
  float s = __expf(q4.x - gm) + __expf(q4.y - gm) + __expf(q4.z - gm) + __expf(q4.w - gm);
#pragma unroll
  for (int sh = 32; sh; sh >>= 1) s += __shfl_xor(s, sh, 64);
  __syncthreads();
  if (l == 0) red[w] = s;
  __syncthreads();
  float gs = red[0] + red[1] + red[2] + red[3];
  sm[t] = __expf(qrow[qr * 256 + t] - gm) / gs;
  __syncthreads();

  float ya[8] = {0.f, 0.f, 0.f, 0.f, 0.f, 0.f, 0.f, 0.f};
  const u16* xs = xbT + (size_t)slab * (NLEN * EMBED) + (size_t)qr * 256 * EMBED;
  for (int ni = 0; ni < 64; ++ni) {
    const int nloc = ni * 4 + w;
    const float sc = sm[nloc];
    u16x8 v = *(const u16x8*)(xs + (size_t)nloc * EMBED + l * 8);
#pragma unroll
    for (int j = 0; j < 8; ++j) ya[j] += sc * bf2f(v[j]);
  }
#pragma unroll
  for (int j = 0; j < 8; ++j) yp[w][l * 8 + j] = ya[j];
  __syncthreads();
  for (int c = t; c < 512; c += 256)
    ypart[((size_t)slab * 4 + qr) * 512 + c] = yp[0][c] + yp[1][c] + yp[2][c] + yp[3][c];
}

// ---------------- attn2: cv[e] = Wk[e]·y + bk[e] ----------------------------
__global__ __launch_bounds__(256) void k_attn2(
    const float* __restrict__ ypart, const float* __restrict__ Wqkv,
    const float* __restrict__ bqkv, float* __restrict__ cv) {
  __shared__ float yl[512];
  const int slab = blockIdx.x >> 2, ec = blockIdx.x & 3;
  const int t = threadIdx.x;
  const int e = ec * 256 + t;
  const float* yb = ypart + (size_t)slab * 4 * 512;
  for (int c = t; c < 512; c += 256)
    yl[c] = yb[c] + yb[512 + c] + yb[1024 + c] + yb[1536 + c];
  __syncthreads();
  const float* wk = Wqkv + (size_t)(1 + e) * EMBED;
  float a = 0.f;
#pragma unroll 4
  for (int c0 = 0; c0 < EMBED; c0 += 4) {
    float4 wv = *(const float4*)(wk + c0);
    a += wv.x * yl[c0] + wv.y * yl[c0 + 1] + wv.z * yl[c0 + 2] + wv.w * yl[c0 + 3];
  }
  cv[(size_t)slab * EXPAND + e] = a + bqkv[1 + e];
}

// ---------------- 256x256 8-phase GEMM core ---------------------------------
// (unchanged from round 3; see comments there)
template <int K, int NT>
__device__ __forceinline__ void gemm256(const u16* __restrict__ Abase,
                                        const u16* __restrict__ Bbase,
                                        u16* lds, f32x4 (&acc)[8][4]) {
  const int t = threadIdx.x;
  const int w = t >> 6, l = t & 63;
  const int wr = w >> 2, wc = w & 3;
  const int lr = l & 15, lj = l >> 4;
  const int rowA0 = wr * 128 + lr;
  const int rowB0 = wc * 64 + lr;

  auto stage = [&](u16* dstBase, const u16* gBase, int kt) {
#pragma unroll
    for (int i = 0; i < 4; ++i) {
      const int s = i * 512 + t;
      const int row = s >> 3;
      const int pch = s & 7;
      gld16(gBase + (size_t)row * K + kt + ((pch ^ (row & 7)) << 3),
            dstBase + s * 8);
    }
  };
  auto rdA = [&](const u16* bufA, int mi, int kc) -> bf16x8 {
    const int row = rowA0 + mi * 16;
    const int ch = kc * 4 + lj;
    return *(const bf16x8*)(bufA + row * 64 + ((ch ^ (row & 7)) << 3));
  };
  auto rdB = [&](const u16* bufB, int ni, int kc) -> bf16x8 {
    const int row = rowB0 + ni * 16;
    const int ch = kc * 4 + lj;
    return *(const bf16x8*)(bufB + row * 64 + ((ch ^ (row & 7)) << 3));
  };

  stage(lds, Abase, 0);
  stage(lds + 16384, Bbase, 0);
  stage(lds + 32768, Abase, 64);
  stage(lds + 49152, Bbase, 64);
  asm volatile("s_waitcnt vmcnt(8)" ::: "memory");
  __builtin_amdgcn_s_barrier();
  __builtin_amdgcn_sched_barrier(0);

#pragma unroll 1
  for (int kt = 0; kt < NT; ++kt) {
    u16* bufA = lds + (kt & 1) * 32768;
    u16* bufB = bufA + 16384;
    const bool st = (kt + 2) < NT;
    const int kt2 = (kt + 2) * 64;
    bf16x8 a0[4][2], a1[4][2], b0[2][2], b1[2][2];

    // ---- phase 1: ds A[M0]+B[N0]; mfma M0N0
#pragma unroll
    for (int mi = 0; mi < 4; ++mi)
#pragma unroll
      for (int kc = 0; kc < 2; ++kc) a0[mi][kc] = rdA(bufA, mi, kc);
#pragma unroll
    for (int ni = 0; ni < 2; ++ni)
#pragma unroll
      for (int kc = 0; kc < 2; ++kc) b0[ni][kc] = rdB(bufB, ni, kc);
    __builtin_amdgcn_s_barrier();
    __builtin_amdgcn_sched_barrier(0);
    __builtin_amdgcn_s_setprio(1);
#pragma unroll
    for (int mi = 0; mi < 4; ++mi)
#pragma unroll
      for (int ni = 0; ni < 2; ++ni)
#pragma unroll
        for (int kc = 0; kc < 2; ++kc)
          acc[mi][ni] = MFMA(a0[mi][kc], b0[ni][kc], acc[mi][ni]);
    __builtin_amdgcn_s_setprio(0);
    __builtin_amdgcn_sched_barrier(0);
    __builtin_amdgcn_s_barrier();
    __builtin_amdgcn_sched_barrier(0);

    // ---- phase 2: ds B[N1]; mfma M0N1
#pragma unroll
    for (int ni = 0; ni < 2; ++ni)
#pragma unroll
      for (int kc = 0; kc < 2; ++kc) b1[ni][kc] = rdB(bufB, ni + 2, kc);
    __builtin_amdgcn_s_barrier();
    __builtin_amdgcn_sched_barrier(0);
    __builtin_amdgcn_s_setprio(1);
#pragma unroll
    for (int mi = 0; mi < 4; ++mi)
#pragma unroll
      for (int ni = 0; ni < 2; ++ni)
#pragma unroll
        for (int kc = 0; kc < 2; ++kc)
          acc[mi][ni + 2] = MFMA(a0[mi][kc], b1[ni][kc], acc[mi][ni + 2]);
    __builtin_amdgcn_s_setprio(0);
    __builtin_amdgcn_sched_barrier(0);
    __builtin_amdgcn_s_barrier();
    __builtin_amdgcn_sched_barrier(0);

    // ---- phase 3: ds A[M1]; stage B(K-tile t+2); mfma M1N1
#pragma unroll
    for (int mi = 0; mi < 4; ++mi)
#pragma unroll
      for (int kc = 0; kc < 2; ++kc) a1[mi][kc] = rdA(bufA, mi + 4, kc);
    if (st) stage(bufB, Bbase, kt2);
    __builtin_amdgcn_s_barrier();
    __builtin_amdgcn_sched_barrier(0);
    __builtin_amdgcn_s_setprio(1);
#pragma unroll
    for (int mi = 0; mi < 4; ++mi)
#pragma unroll
      for (int ni = 0; ni < 2; ++ni)
#pragma unroll
        for (int kc = 0; kc < 2; ++kc)
          acc[mi + 4][ni + 2] = MFMA(a1[mi][kc], b1[ni][kc], acc[mi + 4][ni + 2]);
    __builtin_amdgcn_s_setprio(0);
    __builtin_amdgcn_sched_barrier(0);
    __builtin_amdgcn_s_barrier();
    __builtin_amdgcn_sched_barrier(0);

    // ---- phase 4: stage A(K-tile t+2); mfma M1N0; counted boundary wait
    if (st) stage(bufA, Abase, kt2);
    __builtin_amdgcn_s_barrier();
    __builtin_amdgcn_sched_barrier(0);
    __builtin_amdgcn_s_setprio(1);
#pragma unroll
    for (int mi = 0; mi < 4; ++mi)
#pragma unroll
      for (int ni = 0; ni < 2; ++ni)
#pragma unroll
        for (int kc = 0; kc < 2; ++kc)
          acc[mi + 4][ni] = MFMA(a1[mi][kc], b0[ni][kc], acc[mi + 4][ni]);
    __builtin_amdgcn_s_setprio(0);
    __builtin_amdgcn_sched_barrier(0);
    if (st)
      asm volatile("s_waitcnt vmcnt(8)" ::: "memory");
    else
      asm volatile("s_waitcnt vmcnt(0)" ::: "memory");
    __builtin_amdgcn_s_barrier();
    __builtin_amdgcn_sched_barrier(0);
  }
}

// ---------------- GEMM1: midT[n][e] = relu(valT + bv)*cv, bf16 --------------
// Epilogue: C-tile -> LDS (bf16, chunk^row&7 swizzle) -> 512B-contiguous
// row stores (kills the 2x HBM write amplification of scalar u16 stores).
__global__ __launch_bounds__(512, 2) void k_gemm1(
    const u16* __restrict__ xbT, const u16* __restrict__ WvB,
    const float* __restrict__ bqkv, const float* __restrict__ cv,
    u16* __restrict__ midT) {
  __shared__ __align__(16) u16 lds[65536];  // 128 KB
  const int bid = blockIdx.x;
  const int xc = bid & 7, k = bid >> 3;
  const int te = k & 3;
  const int gg = ((k >> 2) << 3) | xc;  // 0..255
  const int slab = gg >> 2, tn = gg & 3;
  const u16* A = xbT + (size_t)slab * (NLEN * EMBED) + (size_t)tn * 256 * EMBED;
  const u16* B = WvB + (size_t)te * 256 * EMBED;
  f32x4 acc[8][4];
  const f32x4 z = {0.f, 0.f, 0.f, 0.f};
#pragma unroll
  for (int i = 0; i < 8; ++i)
#pragma unroll
    for (int j = 0; j < 4; ++j) acc[i][j] = z;
  gemm256<EMBED, 8>(A, B, lds, acc);
  // K-loop ends with s_barrier; all LDS reads complete -> reuse as C-tile.

  const int t = threadIdx.x, w = t >> 6, l = t & 63;
  const int wr = w >> 2, wc = w & 3;
  const int lr = l & 15, lq4 = (l >> 4) * 4;
  // stage C into LDS [256 n][256 e] bf16, 16B-chunk XOR swizzle (phys = log ^ row&7)
#pragma unroll
  for (int ni = 0; ni < 4; ++ni) {
    const int col = wc * 64 + ni * 16 + lr;
    const int e = te * 256 + col;
    const float bv = bqkv[1 + EXPAND + e];
    const float cve = cv[(size_t)slab * EXPAND + e];
#pragma unroll
    for (int mi = 0; mi < 8; ++mi) {
      const int nr = wr * 128 + mi * 16 + lq4;
#pragma unroll
      for (int r = 0; r < 4; ++r) {
        float v = acc[mi][ni][r] + bv;
        v = v > 0.f ? v * cve : 0.f;
        const int row = nr + r;
        lds[row * 256 + ((((col >> 3) ^ (row & 7)) << 3) | (col & 7))] = f2bf(v);
      }
    }
  }
  __syncthreads();
  // wide stores: wave w owns rows w*32..w*32+31; 2 rows x 32 chunks per iter
  u16* mt = midT + (size_t)slab * (NLEN * EXPAND) + (size_t)te * 256;
#pragma unroll
  for (int it = 0; it < 16; ++it) {
    const int row = w * 32 + it * 2 + (l >> 5);
    const int ch = (l & 31) ^ (row & 7);  // phys chunk holding logical l&31
    uint4 v = *(const uint4*)(lds + row * 256 + ch * 8);
    *(uint4*)(mt + (size_t)(tn * 256 + row) * EXPAND + (l & 31) * 8) = v;
  }
}

// ---------------- GEMM2: out = Wout*mid + bout ------------------------------
__global__ __launch_bounds__(512, 2) void k_gemm2(
    const u16* __restrict__ midT, const u16* __restrict__ WoutB,
    const float* __restrict__ bout, float* __restrict__ out) {
  __shared__ __align__(16) u16 lds[65536];  // 128 KB
  const int bid = blockIdx.x;
  const int xc = bid & 7, k = bid >> 3;
  const int to = k & 1;
  const int gg = ((k >> 1) << 3) | xc;  // 0..255
  const int slab = gg >> 2, tn = gg & 3;
  const int b = slab >> 4, p = slab & 15;
  const u16* A = midT + (size_t)slab * (NLEN * EXPAND) + (size_t)tn * 256 * EXPAND;
  const u16* B = WoutB + (size_t)to * 256 * EXPAND;
  f32x4 acc[8][4];
  const f32x4 z = {0.f, 0.f, 0.f, 0.f};
#pragma unroll
  for (int i = 0; i < 8; ++i)
#pragma unroll
    for (int j = 0; j < 4; ++j) acc[i][j] = z;
  gemm256<EXPAND, 16>(A, B, lds, acc);

  const int t = threadIdx.x, w = t >> 6, l = t & 63;
  const int wr = w >> 2, wc = w & 3;
  const int lr = l & 15, lq4 = (l >> 4) * 4;
  float* ob = out + (size_t)b * (EMBED * CHW) + (size_t)p * NLEN;
#pragma unroll
  for (int ni = 0; ni < 4; ++ni) {
    const int o = to * 256 + wc * 64 + ni * 16 + lr;
    const float bo = bout[o];
#pragma unroll
    for (int mi = 0; mi < 8; ++mi) {
      const int nr = tn * 256 + wr * 128 + mi * 16 + lq4;
      float4 v;
      v.x = acc[mi][ni][0] + bo;
      v.y = acc[mi][ni][1] + bo;
      v.z = acc[mi][ni][2] + bo;
      v.w = acc[mi][ni][3] + bo;
      *(float4*)(ob + (size_t)o * CHW + nr) = v;
    }
  }
}

extern "C" void kernel_launch(void* const* d_in, const int* in_sizes, int n_in,
                              void* d_out, int out_size, void* d_ws, size_t ws_size,
                              hipStream_t stream) {
  const float* x = (const float*)d_in[0];
  const float* Wqkv = (const float*)d_in[1];
  const float* bqkv = (const float*)d_in[2];
  const float* Wout = (const float*)d_in[3];
  const float* bout = (const float*)d_in[4];
  float* out = (float*)d_out;

  char* ws = (char*)d_ws;
  u16* xbT = (u16*)ws;                  // 67108864 B
  u16* WvB = (u16*)(ws + 67108864);     // 1048576 B
  u16* WoutB = (u16*)(ws + 68157440);   // 1048576 B
  float* q = (float*)(ws + 69206016);   // 262144 B
  float* cv = (float*)(ws + 69468160);  // 262144 B
  u16* midT = (u16*)(ws + 69730304);    // 134217728 B
  float* ypart = (float*)(ws + 69730304);  // aliases midT head (attn2 before gemm1)

  k_convert_w<<<1024, 256, 0, stream>>>(Wqkv, Wout, WvB, WoutB);
  k_convert_x<<<1024, 256, 0, stream>>>(x, Wqkv, q, xbT);
  k_attn1<<<256, 256, 0, stream>>>(q, xbT, ypart);
  k_attn2<<<256, 256, 0, stream>>>(ypart, Wqkv, bqkv, cv);
  k_gemm1<<<1024, 512, 0, stream>>>(xbT, WvB, bqkv, cv, midT);
  k_gemm2<<<512, 512, 0, stream>>>(midT, WoutB, bout, out);
}

// Round 5
// 267.709 us; speedup vs baseline: 1.3828x; 1.1227x over previous
//
#include <hip/hip_runtime.h>

#define EMBED 512
#define EXPAND 1024
#define PNUM 16
#define NLEN 1024
#define CHW (PNUM * NLEN)  // 16384
#define SLABS 64

typedef unsigned short u16;
typedef unsigned int u32;
typedef __bf16 bf16x8 __attribute__((ext_vector_type(8)));
typedef u16 u16x8 __attribute__((ext_vector_type(8)));
typedef float f32x4 __attribute__((ext_vector_type(4)));

__device__ __forceinline__ u16 f2bf(float f) {
  u32 u = __builtin_bit_cast(u32, f);
  return (u16)((u + 0x7FFFu + ((u >> 16) & 1u)) >> 16);
}
__device__ __forceinline__ float bf2f(u16 h) {
  return __builtin_bit_cast(float, (u32)h << 16);
}
__device__ __forceinline__ void gld16(const u16* g, u16* l) {
  __builtin_amdgcn_global_load_lds((__attribute__((address_space(1))) void*)g,
                                   (__attribute__((address_space(3))) void*)l,
                                   16, 0, 0);
}
__device__ __forceinline__ f32x4 MFMA(bf16x8 a, bf16x8 b, f32x4 c) {
  return __builtin_amdgcn_mfma_f32_16x16x32_bf16(a, b, c, 0, 0, 0);
}

// ---------------- Kernel W: weights fp32 -> bf16 ----------------
__global__ __launch_bounds__(256) void k_convert_w(
    const float* __restrict__ Wqkv, const float* __restrict__ Wout,
    u16* __restrict__ WvB, u16* __restrict__ WoutB) {
  const int NV = EXPAND * EMBED;  // 524288
  int idx = (blockIdx.x * 256 + threadIdx.x) * 4;
  if (idx < NV) {
    float4 v = *(const float4*)(Wqkv + (size_t)(1 + EXPAND) * EMBED + idx);
    uint2 u = make_uint2((u32)f2bf(v.x) | ((u32)f2bf(v.y) << 16),
                         (u32)f2bf(v.z) | ((u32)f2bf(v.w) << 16));
    *(uint2*)(WvB + idx) = u;
  } else {
    int j = idx - NV;
    float4 v = *(const float4*)(Wout + j);
    uint2 u = make_uint2((u32)f2bf(v.x) | ((u32)f2bf(v.y) << 16),
                         (u32)f2bf(v.z) | ((u32)f2bf(v.w) << 16));
    *(uint2*)(WoutB + j) = u;
  }
}

// ---------------- Kernel A: x -> bf16 transposed + query GEMV ---------------
// LDS-transpose version. Block = 128-n window x 512 c (8 chunks of 64 c).
// Read: thread owns 8c x 4n via float4 (wave instr = 8 x 128B full lines).
// Reg-transpose -> LDS [128n][64c] bf16, 16B-chunk swizzle ch^=(nl&7).
// Write-out: lane octets stream 128B-contiguous xbT row segments.
__global__ __launch_bounds__(256) void k_convert_x(
    const float* __restrict__ x, const float* __restrict__ Wqkv,
    float* __restrict__ q, u16* __restrict__ xbT) {
  __shared__ __align__(16) u16 tile[128 * 64];  // 16 KB
  __shared__ float qp[256 * 4];                 // 4 KB
  const int slab = blockIdx.x >> 3, nw = blockIdx.x & 7;
  const int b = slab >> 4, p = slab & 15;
  const int t = threadIdx.x;
  const int c8 = t & 7;   // c-octet index within 64-c chunk
  const int ng = t >> 3;  // n-group (0..31): n = ng*4..+3
  const float* xs = x + (size_t)b * (EMBED * CHW) + (size_t)p * NLEN + nw * 128;
  u16* dst = xbT + (size_t)slab * (NLEN * EMBED) + (size_t)(nw * 128) * EMBED;
  float qa[4] = {0.f, 0.f, 0.f, 0.f};

  for (int cc = 0; cc < 8; ++cc) {
    const int cbase = cc * 64;
    float4 v[8];
#pragma unroll
    for (int k = 0; k < 8; ++k)
      v[k] = *(const float4*)(xs + (size_t)(cbase + c8 * 8 + k) * CHW + ng * 4);
    const float* w0 = Wqkv + cbase + c8 * 8;
#pragma unroll
    for (int k = 0; k < 8; ++k) {
      qa[0] += w0[k] * v[k].x;
      qa[1] += w0[k] * v[k].y;
      qa[2] += w0[k] * v[k].z;
      qa[3] += w0[k] * v[k].w;
    }
    // register transpose: 4 n-rows x 8 packed bf16 -> swizzled LDS uint4
#pragma unroll
    for (int j = 0; j < 4; ++j) {
      const int nl = ng * 4 + j;
      float e[8];
#pragma unroll
      for (int k = 0; k < 8; ++k)
        e[k] = (j == 0) ? v[k].x : (j == 1) ? v[k].y : (j == 2) ? v[k].z : v[k].w;
      uint4 pk;
      pk.x = (u32)f2bf(e[0]) | ((u32)f2bf(e[1]) << 16);
      pk.y = (u32)f2bf(e[2]) | ((u32)f2bf(e[3]) << 16);
      pk.z = (u32)f2bf(e[4]) | ((u32)f2bf(e[5]) << 16);
      pk.w = (u32)f2bf(e[6]) | ((u32)f2bf(e[7]) << 16);
      *(uint4*)(tile + nl * 64 + ((c8 ^ (nl & 7)) << 3)) = pk;
    }
    __syncthreads();
    // write-out: s = m*256+t; nl = s>>3, ch = s&7 -> 8 rows x 128B per wave instr
#pragma unroll
    for (int m = 0; m < 4; ++m) {
      const int s = m * 256 + t;
      const int nl = s >> 3, ch = s & 7;
      uint4 vv = *(const uint4*)(tile + nl * 64 + ((ch ^ (nl & 7)) << 3));
      *(uint4*)(dst + (size_t)nl * EMBED + cbase + ch * 8) = vv;
    }
    __syncthreads();
  }
  // q reduction: n_local owned by 8 threads (ng = n>>2, c8 = 0..7)
  qp[t * 4 + 0] = qa[0];
  qp[t * 4 + 1] = qa[1];
  qp[t * 4 + 2] = qa[2];
  qp[t * 4 + 3] = qa[3];
  __syncthreads();
  if (t < 128) {
    float a = 0.f;
#pragma unroll
    for (int o = 0; o < 8; ++o) a += qp[((((t >> 2) << 3) + o) << 2) + (t & 3)];
    q[(size_t)slab * NLEN + nw * 128 + t] = a;
  }
}

// ---------------- attn1: softmax + partial y over an n-quarter --------------
__global__ __launch_bounds__(256) void k_attn1(
    const float* __restrict__ q, const u16* __restrict__ xbT,
    float* __restrict__ ypart) {
  __shared__ float red[4];
  __shared__ float sm[256];
  __shared__ float yp[4][512];
  const int slab = blockIdx.x >> 2, qr = blockIdx.x & 3;
  const int t = threadIdx.x, w = t >> 6, l = t & 63;
  const float* qrow = q + (size_t)slab * NLEN;

  float4 q4 = ((const float4*)qrow)[t];
  float m = fmaxf(fmaxf(q4.x, q4.y), fmaxf(q4.z, q4.w));
#pragma unroll
  for (int sh = 32; sh; sh >>= 1) m = fmaxf(m, __shfl_xor(m, sh, 64));
  if (l == 0) red[w] = m;
  __syncthreads();
  float gm = fmaxf(fmaxf(red[0], red[1]), fmaxf(red[2], red[3]));
  float s = __expf(q4.x - gm) + __expf(q4.y - gm) + __expf(q4.z - gm) + __expf(q4.w - gm);
#pragma unroll
  for (int sh = 32; sh; sh >>= 1) s += __shfl_xor(s, sh, 64);
  __syncthreads();
  if (l == 0) red[w] = s;
  __syncthreads();
  float gs = red[0] + red[1] + red[2] + red[3];
  sm[t] = __expf(qrow[qr * 256 + t] - gm) / gs;
  __syncthreads();

  float ya[8] = {0.f, 0.f, 0.f, 0.f, 0.f, 0.f, 0.f, 0.f};
  const u16* xs = xbT + (size_t)slab * (NLEN * EMBED) + (size_t)qr * 256 * EMBED;
  for (int ni = 0; ni < 64; ++ni) {
    const int nloc = ni * 4 + w;
    const float sc = sm[nloc];
    u16x8 v = *(const u16x8*)(xs + (size_t)nloc * EMBED + l * 8);
#pragma unroll
    for (int j = 0; j < 8; ++j) ya[j] += sc * bf2f(v[j]);
  }
#pragma unroll
  for (int j = 0; j < 8; ++j) yp[w][l * 8 + j] = ya[j];
  __syncthreads();
  for (int c = t; c < 512; c += 256)
    ypart[((size_t)slab * 4 + qr) * 512 + c] = yp[0][c] + yp[1][c] + yp[2][c] + yp[3][c];
}

// ---------------- attn2: cv[e] = Wk[e]·y + bk[e] ----------------------------
__global__ __launch_bounds__(256) void k_attn2(
    const float* __restrict__ ypart, const float* __restrict__ Wqkv,
    const float* __restrict__ bqkv, float* __restrict__ cv) {
  __shared__ float yl[512];
  const int slab = blockIdx.x >> 2, ec = blockIdx.x & 3;
  const int t = threadIdx.x;
  const int e = ec * 256 + t;
  const float* yb = ypart + (size_t)slab * 4 * 512;
  for (int c = t; c < 512; c += 256)
    yl[c] = yb[c] + yb[512 + c] + yb[1024 + c] + yb[1536 + c];
  __syncthreads();
  const float* wk = Wqkv + (size_t)(1 + e) * EMBED;
  float a = 0.f;
#pragma unroll 4
  for (int c0 = 0; c0 < EMBED; c0 += 4) {
    float4 wv = *(const float4*)(wk + c0);
    a += wv.x * yl[c0] + wv.y * yl[c0 + 1] + wv.z * yl[c0 + 2] + wv.w * yl[c0 + 3];
  }
  cv[(size_t)slab * EXPAND + e] = a + bqkv[1 + e];
}

// ---------------- 256x256 8-phase GEMM core ---------------------------------
template <int K, int NT>
__device__ __forceinline__ void gemm256(const u16* __restrict__ Abase,
                                        const u16* __restrict__ Bbase,
                                        u16* lds, f32x4 (&acc)[8][4]) {
  const int t = threadIdx.x;
  const int w = t >> 6, l = t & 63;
  const int wr = w >> 2, wc = w & 3;
  const int lr = l & 15, lj = l >> 4;
  const int rowA0 = wr * 128 + lr;
  const int rowB0 = wc * 64 + lr;

  auto stage = [&](u16* dstBase, const u16* gBase, int kt) {
#pragma unroll
    for (int i = 0; i < 4; ++i) {
      const int s = i * 512 + t;
      const int row = s >> 3;
      const int pch = s & 7;
      gld16(gBase + (size_t)row * K + kt + ((pch ^ (row & 7)) << 3),
            dstBase + s * 8);
    }
  };
  auto rdA = [&](const u16* bufA, int mi, int kc) -> bf16x8 {
    const int row = rowA0 + mi * 16;
    const int ch = kc * 4 + lj;
    return *(const bf16x8*)(bufA + row * 64 + ((ch ^ (row & 7)) << 3));
  };
  auto rdB = [&](const u16* bufB, int ni, int kc) -> bf16x8 {
    const int row = rowB0 + ni * 16;
    const int ch = kc * 4 + lj;
    return *(const bf16x8*)(bufB + row * 64 + ((ch ^ (row & 7)) << 3));
  };

  stage(lds, Abase, 0);
  stage(lds + 16384, Bbase, 0);
  stage(lds + 32768, Abase, 64);
  stage(lds + 49152, Bbase, 64);
  asm volatile("s_waitcnt vmcnt(8)" ::: "memory");
  __builtin_amdgcn_s_barrier();
  __builtin_amdgcn_sched_barrier(0);

#pragma unroll 1
  for (int kt = 0; kt < NT; ++kt) {
    u16* bufA = lds + (kt & 1) * 32768;
    u16* bufB = bufA + 16384;
    const bool st = (kt + 2) < NT;
    const int kt2 = (kt + 2) * 64;
    bf16x8 a0[4][2], a1[4][2], b0[2][2], b1[2][2];

    // ---- phase 1: ds A[M0]+B[N0]; mfma M0N0
#pragma unroll
    for (int mi = 0; mi < 4; ++mi)
#pragma unroll
      for (int kc = 0; kc < 2; ++kc) a0[mi][kc] = rdA(bufA, mi, kc);
#pragma unroll
    for (int ni = 0; ni < 2; ++ni)
#pragma unroll
      for (int kc = 0; kc < 2; ++kc) b0[ni][kc] = rdB(bufB, ni, kc);
    __builtin_amdgcn_s_barrier();
    __builtin_amdgcn_sched_barrier(0);
    __builtin_amdgcn_s_setprio(1);
#pragma unroll
    for (int mi = 0; mi < 4; ++mi)
#pragma unroll
      for (int ni = 0; ni < 2; ++ni)
#pragma unroll
        for (int kc = 0; kc < 2; ++kc)
          acc[mi][ni] = MFMA(a0[mi][kc], b0[ni][kc], acc[mi][ni]);
    __builtin_amdgcn_s_setprio(0);
    __builtin_amdgcn_sched_barrier(0);
    __builtin_amdgcn_s_barrier();
    __builtin_amdgcn_sched_barrier(0);

    // ---- phase 2: ds B[N1]; mfma M0N1
#pragma unroll
    for (int ni = 0; ni < 2; ++ni)
#pragma unroll
      for (int kc = 0; kc < 2; ++kc) b1[ni][kc] = rdB(bufB, ni + 2, kc);
    __builtin_amdgcn_s_barrier();
    __builtin_amdgcn_sched_barrier(0);
    __builtin_amdgcn_s_setprio(1);
#pragma unroll
    for (int mi = 0; mi < 4; ++mi)
#pragma unroll
      for (int ni = 0; ni < 2; ++ni)
#pragma unroll
        for (int kc = 0; kc < 2; ++kc)
          acc[mi][ni + 2] = MFMA(a0[mi][kc], b1[ni][kc], acc[mi][ni + 2]);
    __builtin_amdgcn_s_setprio(0);
    __builtin_amdgcn_sched_barrier(0);
    __builtin_amdgcn_s_barrier();
    __builtin_amdgcn_sched_barrier(0);

    // ---- phase 3: ds A[M1]; stage B(K-tile t+2); mfma M1N1
#pragma unroll
    for (int mi = 0; mi < 4; ++mi)
#pragma unroll
      for (int kc = 0; kc < 2; ++kc) a1[mi][kc] = rdA(bufA, mi + 4, kc);
    if (st) stage(bufB, Bbase, kt2);
    __builtin_amdgcn_s_barrier();
    __builtin_amdgcn_sched_barrier(0);
    __builtin_amdgcn_s_setprio(1);
#pragma unroll
    for (int mi = 0; mi < 4; ++mi)
#pragma unroll
      for (int ni = 0; ni < 2; ++ni)
#pragma unroll
        for (int kc = 0; kc < 2; ++kc)
          acc[mi + 4][ni + 2] = MFMA(a1[mi][kc], b1[ni][kc], acc[mi + 4][ni + 2]);
    __builtin_amdgcn_s_setprio(0);
    __builtin_amdgcn_sched_barrier(0);
    __builtin_amdgcn_s_barrier();
    __builtin_amdgcn_sched_barrier(0);

    // ---- phase 4: stage A(K-tile t+2); mfma M1N0; counted boundary wait
    if (st) stage(bufA, Abase, kt2);
    __builtin_amdgcn_s_barrier();
    __builtin_amdgcn_sched_barrier(0);
    __builtin_amdgcn_s_setprio(1);
#pragma unroll
    for (int mi = 0; mi < 4; ++mi)
#pragma unroll
      for (int ni = 0; ni < 2; ++ni)
#pragma unroll
        for (int kc = 0; kc < 2; ++kc)
          acc[mi + 4][ni] = MFMA(a1[mi][kc], b0[ni][kc], acc[mi + 4][ni]);
    __builtin_amdgcn_s_setprio(0);
    __builtin_amdgcn_sched_barrier(0);
    if (st)
      asm volatile("s_waitcnt vmcnt(8)" ::: "memory");
    else
      asm volatile("s_waitcnt vmcnt(0)" ::: "memory");
    __builtin_amdgcn_s_barrier();
    __builtin_amdgcn_sched_barrier(0);
  }
}

// ---------------- GEMM1: midT[n][e] = relu(valT + bv)*cv, bf16 --------------
__global__ __launch_bounds__(512, 2) void k_gemm1(
    const u16* __restrict__ xbT, const u16* __restrict__ WvB,
    const float* __restrict__ bqkv, const float* __restrict__ cv,
    u16* __restrict__ midT) {
  __shared__ __align__(16) u16 lds[65536];  // 128 KB
  const int bid = blockIdx.x;
  const int xc = bid & 7, k = bid >> 3;
  const int te = k & 3;
  const int gg = ((k >> 2) << 3) | xc;  // 0..255
  const int slab = gg >> 2, tn = gg & 3;
  const u16* A = xbT + (size_t)slab * (NLEN * EMBED) + (size_t)tn * 256 * EMBED;
  const u16* B = WvB + (size_t)te * 256 * EMBED;
  f32x4 acc[8][4];
  const f32x4 z = {0.f, 0.f, 0.f, 0.f};
#pragma unroll
  for (int i = 0; i < 8; ++i)
#pragma unroll
    for (int j = 0; j < 4; ++j) acc[i][j] = z;
  gemm256<EMBED, 8>(A, B, lds, acc);

  const int t = threadIdx.x, w = t >> 6, l = t & 63;
  const int wr = w >> 2, wc = w & 3;
  const int lr = l & 15, lq4 = (l >> 4) * 4;
#pragma unroll
  for (int ni = 0; ni < 4; ++ni) {
    const int col = wc * 64 + ni * 16 + lr;
    const int e = te * 256 + col;
    const float bv = bqkv[1 + EXPAND + e];
    const float cve = cv[(size_t)slab * EXPAND + e];
#pragma unroll
    for (int mi = 0; mi < 8; ++mi) {
      const int nr = wr * 128 + mi * 16 + lq4;
#pragma unroll
      for (int r = 0; r < 4; ++r) {
        float v = acc[mi][ni][r] + bv;
        v = v > 0.f ? v * cve : 0.f;
        const int row = nr + r;
        lds[row * 256 + ((((col >> 3) ^ (row & 7)) << 3) | (col & 7))] = f2bf(v);
      }
    }
  }
  __syncthreads();
  u16* mt = midT + (size_t)slab * (NLEN * EXPAND) + (size_t)te * 256;
#pragma unroll
  for (int it = 0; it < 16; ++it) {
    const int row = w * 32 + it * 2 + (l >> 5);
    const int ch = (l & 31) ^ (row & 7);
    uint4 v = *(const uint4*)(lds + row * 256 + ch * 8);
    *(uint4*)(mt + (size_t)(tn * 256 + row) * EXPAND + (l & 31) * 8) = v;
  }
}

// ---------------- GEMM2: out = Wout*mid + bout ------------------------------
__global__ __launch_bounds__(512, 2) void k_gemm2(
    const u16* __restrict__ midT, const u16* __restrict__ WoutB,
    const float* __restrict__ bout, float* __restrict__ out) {
  __shared__ __align__(16) u16 lds[65536];  // 128 KB
  const int bid = blockIdx.x;
  const int xc = bid & 7, k = bid >> 3;
  const int to = k & 1;
  const int gg = ((k >> 1) << 3) | xc;  // 0..255
  const int slab = gg >> 2, tn = gg & 3;
  const int b = slab >> 4, p = slab & 15;
  const u16* A = midT + (size_t)slab * (NLEN * EXPAND) + (size_t)tn * 256 * EXPAND;
  const u16* B = WoutB + (size_t)to * 256 * EXPAND;
  f32x4 acc[8][4];
  const f32x4 z = {0.f, 0.f, 0.f, 0.f};
#pragma unroll
  for (int i = 0; i < 8; ++i)
#pragma unroll
    for (int j = 0; j < 4; ++j) acc[i][j] = z;
  gemm256<EXPAND, 16>(A, B, lds, acc);

  const int t = threadIdx.x, w = t >> 6, l = t & 63;
  const int wr = w >> 2, wc = w & 3;
  const int lr = l & 15, lq4 = (l >> 4) * 4;
  float* ob = out + (size_t)b * (EMBED * CHW) + (size_t)p * NLEN;
#pragma unroll
  for (int ni = 0; ni < 4; ++ni) {
    const int o = to * 256 + wc * 64 + ni * 16 + lr;
    const float bo = bout[o];
#pragma unroll
    for (int mi = 0; mi < 8; ++mi) {
      const int nr = tn * 256 + wr * 128 + mi * 16 + lq4;
      float4 v;
      v.x = acc[mi][ni][0] + bo;
      v.y = acc[mi][ni][1] + bo;
      v.z = acc[mi][ni][2] + bo;
      v.w = acc[mi][ni][3] + bo;
      *(float4*)(ob + (size_t)o * CHW + nr) = v;
    }
  }
}

extern "C" void kernel_launch(void* const* d_in, const int* in_sizes, int n_in,
                              void* d_out, int out_size, void* d_ws, size_t ws_size,
                              hipStream_t stream) {
  const float* x = (const float*)d_in[0];
  const float* Wqkv = (const float*)d_in[1];
  const float* bqkv = (const float*)d_in[2];
  const float* Wout = (const float*)d_in[3];
  const float* bout = (const float*)d_in[4];
  float* out = (float*)d_out;

  char* ws = (char*)d_ws;
  u16* xbT = (u16*)ws;                  // 67108864 B
  u16* WvB = (u16*)(ws + 67108864);     // 1048576 B
  u16* WoutB = (u16*)(ws + 68157440);   // 1048576 B
  float* q = (float*)(ws + 69206016);   // 262144 B
  float* cv = (float*)(ws + 69468160);  // 262144 B
  u16* midT = (u16*)(ws + 69730304);    // 134217728 B
  float* ypart = (float*)(ws + 69730304);  // aliases midT head (attn2 before gemm1)

  k_convert_w<<<1024, 256, 0, stream>>>(Wqkv, Wout, WvB, WoutB);
  k_convert_x<<<512, 256, 0, stream>>>(x, Wqkv, q, xbT);
  k_attn1<<<256, 256, 0, stream>>>(q, xbT, ypart);
  k_attn2<<<256, 256, 0, stream>>>(ypart, Wqkv, bqkv, cv);
  k_gemm1<<<1024, 512, 0, stream>>>(xbT, WvB, bqkv, cv, midT);
  k_gemm2<<<512, 512, 0, stream>>>(midT, WoutB, bout, out);
}